// Round 6
// baseline (389.631 us; speedup 1.0000x reference)
//
#include <hip/hip_runtime.h>

#define N_NODES 100000
#define N_EDGES 3200000
#define D_NODE 128
#define D_EDGE 16

#define NR 7                 // node ranges == buckets; SPAN*NR >= N_NODES
#define SPAN 16384           // pow2: bucket = r>>14, local = r & 16383
#define CAP 560000           // per-bucket capacity (expected 524288 +- ~700)
#define NSLICE 64            // K2 blocks per range -> 448 blocks

#define K1_THREADS 256
#define K1_EDGES 512         // edges per K1 block; 3.2M/512 = 6250 blocks exact
#define NW (K1_THREADS / 64) // 4 waves per block
#define K1_ROUNDS (K1_EDGES / K1_THREADS)   // 2

// ---- ws layout (float units) ----
#define WS_X     0                         // 100000: compacted nodes[:,0]
#define WS_CNT   100000                    // 8 ints: bucket counters
#define WS_OVF   100008                    // 100000: overflow accumulator (stat. never)
#define WS_BKT   200008                    // NR*CAP*2 floats of (local,msg) pairs; 8B-aligned
#define WS_PART  (WS_BKT + NR * CAP * 2)   // NSLICE rows x N_NODES partials
#define WS_TOTAL (WS_PART + NSLICE * N_NODES)   // ~57.8 MB

// clang-native vectors (__builtin_nontemporal_load rejects HIP's class-type int4)
typedef int   iv2 __attribute__((ext_vector_type(2)));
typedef int   iv4 __attribute__((ext_vector_type(4)));
typedef float fv4 __attribute__((ext_vector_type(4)));

// ---------------------------------------------------------------------------
// K0: zero counters + overflow acc, compact node column.
// ---------------------------------------------------------------------------
__global__ void v4_init(const float* __restrict__ nodes,
                        float* __restrict__ x,
                        float* __restrict__ ovf,
                        int*   __restrict__ cnt) {
    int i = blockIdx.x * blockDim.x + threadIdx.x;
    if (i < 8) cnt[i] = 0;
    if (i < N_NODES) {
        x[i]   = nodes[(size_t)i * D_NODE];
        ovf[i] = 0.f;
    }
}

// ---------------------------------------------------------------------------
// K1: compute msg and partition (local,msg) into NR range-buckets.
// Round-5 post-mortem: 56KB LDS (2 blocks/CU) + 1024 same-address LDS atomics
// per block + divergent search copy-out made this ~2-3x its memory cost.
// This version: 28KB LDS (20 waves/CU), ballot-rank placement (7 ballots per
// wave -> exact positions, ZERO LDS atomics), per-bucket cooperative copy-out.
// Global bucket counters: 7 atomics per block (43.75K total, nowhere near the
// 3.2M memory-side RMWs that rounds 3/4 proved fatal).
// ---------------------------------------------------------------------------
__global__ __launch_bounds__(K1_THREADS) void v4_bucketize(
        const float* __restrict__ x,
        const float* __restrict__ edges,
        const int*   __restrict__ senders,
        const int*   __restrict__ receivers,
        const float* __restrict__ w_node,
        const float* __restrict__ w_edge,
        int*   __restrict__ cnt,
        float* __restrict__ ovf,
        int*   __restrict__ bkt) {
    __shared__ iv2 s_pair[NR][K1_EDGES];         // 28 KB
    __shared__ int s_wcnt[NW][NR];
    __shared__ int s_wbase[NW][NR];
    __shared__ int s_fill[NR];
    __shared__ int s_gbase[NR];

    const float wn = w_node[0];
    const float we = w_edge[0];
    const int tile = blockIdx.x * K1_EDGES;
    const int lane = threadIdx.x & 63;
    const int wv   = threadIdx.x >> 6;
    const unsigned long long lt = (1ull << lane) - 1ull;

    if (threadIdx.x < NR) s_fill[threadIdx.x] = 0;

    // issue all global loads up front (max MLP before the barrier ladder)
    int rr[K1_ROUNDS]; float mm[K1_ROUNDS];
#pragma unroll
    for (int j = 0; j < K1_ROUNDS; ++j) {
        int e    = tile + j * K1_THREADS + (int)threadIdx.x;
        rr[j]    = __builtin_nontemporal_load(receivers + e);
        int s    = __builtin_nontemporal_load(senders + e);
        float ev = __builtin_nontemporal_load(edges + (size_t)e * D_EDGE);
        mm[j] = we * ev + wn * x[s];
    }
    __syncthreads();                              // s_fill init visible

#pragma unroll
    for (int j = 0; j < K1_ROUNDS; ++j) {
        const int b = rr[j] >> 14;                // SPAN = 2^14
        int rank = 0, wcount = 0;
#pragma unroll
        for (int k = 0; k < NR; ++k) {
            unsigned long long mk = __ballot(b == k);
            if (k == b)    rank   = __popcll(mk & lt);
            if (lane == k) wcount = __popcll(mk);
        }
        if (lane < NR) s_wcnt[wv][lane] = wcount;
        __syncthreads();
        if (threadIdx.x < NR) {                   // exclusive scan over 4 waves
            int bb = threadIdx.x;
            int base = s_fill[bb];
#pragma unroll
            for (int w = 0; w < NW; ++w) { s_wbase[w][bb] = base; base += s_wcnt[w][bb]; }
            s_fill[bb] = base;
        }
        __syncthreads();
        iv2 v; v.x = rr[j] & (SPAN - 1); v.y = __float_as_int(mm[j]);
        s_pair[b][s_wbase[wv][b] + rank] = v;     // conflict-free: ranks consecutive
        __syncthreads();
    }

    if (threadIdx.x < NR)
        s_gbase[threadIdx.x] = atomicAdd(&cnt[threadIdx.x], s_fill[threadIdx.x]);
    __syncthreads();

#pragma unroll
    for (int b = 0; b < NR; ++b) {
        const int n  = s_fill[b];
        const int gb = s_gbase[b];
        if (gb + n <= CAP) {                      // fast path (always, in practice)
            for (int i = threadIdx.x; i < n; i += K1_THREADS)
                *(iv2*)(bkt + ((size_t)b * CAP + gb + i) * 2) = s_pair[b][i];
        } else {
            for (int i = threadIdx.x; i < n; i += K1_THREADS) {
                iv2 v = s_pair[b][i];
                int gi = gb + i;
                if (gi < CAP) *(iv2*)(bkt + ((size_t)b * CAP + gi) * 2) = v;
                else atomicAdd(&ovf[b * SPAN + v.x], __int_as_float(v.y));
            }
        }
    }
}

// ---------------------------------------------------------------------------
// K2: grid (NSLICE, NR). Block (s,r) reads its contiguous slice of bucket r
// once, LDS-atomicAdds into the 64KB range accumulator, overwrites its span
// of partials row s. bkt/partials are L3-resident (25.6MB each).
// ---------------------------------------------------------------------------
__global__ __launch_bounds__(1024) void v4_accum(
        const int* __restrict__ bkt,
        const int* __restrict__ cnt,
        float* __restrict__ partials) {
    extern __shared__ float acc[];               // SPAN floats = 64 KB dynamic
    const int r  = blockIdx.y;
    const int lo = r * SPAN;
    int span = N_NODES - lo; if (span > SPAN) span = SPAN;

    const int n     = cnt[r];
    const int chunk = (n + NSLICE - 1) / NSLICE;
    int start = blockIdx.x * chunk;
    int end   = start + chunk; if (end > n) end = n;

    for (int i = threadIdx.x * 4; i < SPAN; i += 4096) {
        fv4 z = {0.f, 0.f, 0.f, 0.f};
        *(fv4*)(acc + i) = z;
    }
    __syncthreads();

    const int* base = bkt + (size_t)r * CAP * 2;
    for (int i = start + (int)threadIdx.x; i < end; i += 1024) {
        iv2 v = *(const iv2*)(base + (size_t)i * 2);
        atomicAdd(&acc[v.x], __int_as_float(v.y));
    }
    __syncthreads();

    float* dst = partials + (size_t)blockIdx.x * N_NODES + lo;
    for (int i = threadIdx.x * 4; i < span; i += 4096)   // span % 4 == 0
        *(fv4*)(dst + i) = *(const fv4*)(acc + i);
}

// ---------------------------------------------------------------------------
// K3: out[i] = wn*x[i] + b + ovf[i] + sum_s partials[s][i].
// ---------------------------------------------------------------------------
__global__ void v4_out(const float* __restrict__ x,
                       const float* __restrict__ partials,
                       const float* __restrict__ ovf,
                       const float* __restrict__ w_node,
                       const float* __restrict__ b_node,
                       float* __restrict__ out) {
    int i = blockIdx.x * blockDim.x + threadIdx.x;
    if (i >= N_NODES) return;
    float s = w_node[0] * x[i] + b_node[0] + ovf[i];
#pragma unroll 8
    for (int c = 0; c < NSLICE; ++c) s += partials[(size_t)c * N_NODES + i];
    out[i] = s;
}

// ---------------------------------------------------------------------------
// Fallback (workspace too small): direct atomic path (known-correct).
// ---------------------------------------------------------------------------
__global__ void tmp_init_out(const float* __restrict__ nodes,
                             const float* __restrict__ w_node,
                             const float* __restrict__ b_node,
                             float* __restrict__ out) {
    int i = blockIdx.x * blockDim.x + threadIdx.x;
    if (i < N_NODES) out[i] = w_node[0] * nodes[(size_t)i * D_NODE] + b_node[0];
}

__global__ void tmp_edge_scatter_direct(const float* __restrict__ nodes,
                                        const float* __restrict__ edges,
                                        const int*   __restrict__ senders,
                                        const int*   __restrict__ receivers,
                                        const float* __restrict__ w_node,
                                        const float* __restrict__ w_edge,
                                        float* __restrict__ out) {
    const float wn = w_node[0];
    const float we = w_edge[0];
    int base = (blockIdx.x * blockDim.x + threadIdx.x) * 4;
    if (base + 3 < N_EDGES) {
        iv4 s = *(const iv4*)(senders + base);
        iv4 r = *(const iv4*)(receivers + base);
        atomicAdd(&out[r.x], we * edges[(size_t)(base + 0) * D_EDGE] + wn * nodes[(size_t)s.x * D_NODE]);
        atomicAdd(&out[r.y], we * edges[(size_t)(base + 1) * D_EDGE] + wn * nodes[(size_t)s.y * D_NODE]);
        atomicAdd(&out[r.z], we * edges[(size_t)(base + 2) * D_EDGE] + wn * nodes[(size_t)s.z * D_NODE]);
        atomicAdd(&out[r.w], we * edges[(size_t)(base + 3) * D_EDGE] + wn * nodes[(size_t)s.w * D_NODE]);
    } else {
        for (int e = base; e < N_EDGES; ++e) {
            atomicAdd(&out[receivers[e]],
                      we * edges[(size_t)e * D_EDGE] + wn * nodes[(size_t)senders[e] * D_NODE]);
        }
    }
}

extern "C" void kernel_launch(void* const* d_in, const int* in_sizes, int n_in,
                              void* d_out, int out_size, void* d_ws, size_t ws_size,
                              hipStream_t stream) {
    const float* nodes     = (const float*)d_in[0];
    const float* edges     = (const float*)d_in[1];
    const int*   senders   = (const int*)d_in[2];
    const int*   receivers = (const int*)d_in[3];
    const float* w_node    = (const float*)d_in[4];
    const float* w_edge    = (const float*)d_in[5];
    const float* b_node    = (const float*)d_in[6];
    float* out = (float*)d_out;
    float* ws  = (float*)d_ws;

    if (ws_size >= (size_t)WS_TOTAL * sizeof(float)) {
        float* x    = ws + WS_X;
        int*   cnt  = (int*)(ws + WS_CNT);
        float* ovf  = ws + WS_OVF;
        int*   bkt  = (int*)(ws + WS_BKT);
        float* part = ws + WS_PART;

        int threads = 256;
        v4_init<<<(N_NODES + threads - 1) / threads, threads, 0, stream>>>(
            nodes, x, ovf, cnt);

        v4_bucketize<<<N_EDGES / K1_EDGES, K1_THREADS, 0, stream>>>(
            x, edges, senders, receivers, w_node, w_edge, cnt, ovf, bkt);

        dim3 grid2(NSLICE, NR);
        v4_accum<<<grid2, 1024, SPAN * sizeof(float), stream>>>(bkt, cnt, part);

        v4_out<<<(N_NODES + threads - 1) / threads, threads, 0, stream>>>(
            x, part, ovf, w_node, b_node, out);
    } else {
        int threads = 256;
        tmp_init_out<<<(N_NODES + threads - 1) / threads, threads, 0, stream>>>(
            nodes, w_node, b_node, out);
        int n_thr = N_EDGES / 4;
        tmp_edge_scatter_direct<<<(n_thr + threads - 1) / threads, threads, 0, stream>>>(
            nodes, edges, senders, receivers, w_node, w_edge, out);
    }
}

// Round 7
// 358.333 us; speedup vs baseline: 1.0873x; 1.0873x over previous
//
#include <hip/hip_runtime.h>

#define N_NODES 100000
#define N_EDGES 3200000
#define D_NODE 128
#define D_EDGE 16

#define NR 7                 // node ranges == buckets; SPAN*NR >= N_NODES
#define SPAN 16384           // pow2: bucket = r>>14, local = r & 16383
#define CAP 560000           // per-bucket capacity (expected 524288 +- ~663 sigma)
#define NSLICE 64            // K2 blocks per range -> 448 blocks

#define K1_THREADS 256
#define K1_EDGES 1024        // edges per K1 block; 3.2M/1024 = 3125 blocks exact
#define NW (K1_THREADS / 64) // 4 waves
#define K1_ROUNDS (K1_EDGES / K1_THREADS)   // 4

// ---- ws layout (float units) ----
#define WS_X     0                         // 100000: compacted nodes[:,0]
#define WS_CNT   100000                    // 8 ints: bucket counters
#define WS_OVF   100008                    // 100000: overflow accumulator (stat. never)
#define WS_BKT   200008                    // NR*CAP*2 floats of (local,msg) pairs
#define WS_PART  (WS_BKT + NR * CAP * 2)   // NSLICE rows x N_NODES partials
#define WS_TOTAL (WS_PART + NSLICE * N_NODES)   // ~57.8 MB

// clang-native vectors (__builtin_nontemporal_load rejects HIP's class-type int4)
typedef int   iv2 __attribute__((ext_vector_type(2)));
typedef int   iv4 __attribute__((ext_vector_type(4)));
typedef float fv4 __attribute__((ext_vector_type(4)));

// ---------------------------------------------------------------------------
// K0: zero counters + overflow acc, compact node column.
// ---------------------------------------------------------------------------
__global__ void v5_init(const float* __restrict__ nodes,
                        float* __restrict__ x,
                        float* __restrict__ ovf,
                        int*   __restrict__ cnt) {
    int i = blockIdx.x * blockDim.x + threadIdx.x;
    if (i < 8) cnt[i] = 0;
    if (i < N_NODES) {
        x[i]   = nodes[(size_t)i * D_NODE];
        ovf[i] = 0.f;
    }
}

// ---------------------------------------------------------------------------
// K1 v5: count-then-write-direct bucketize.
// Round-5 (LDS-atomic staging + search copy-out, 56KB LDS): pipeline 123us.
// Round-6 (ballot staging, 28KB LDS, 6 barriers): +22us — staging round-trip
// through LDS is the cost. v5 removes the LDS pair round-trip entirely:
//   pass A: 7 ballots/round -> per-wave bucket counts + in-wave ranks, all in
//           REGISTERS; tiny LDS exchange (112 ints); 7 global counter atomics
//           per block (21.9K total).
//   pass B: each thread writes its (local,msg) pair STRAIGHT to its global
//           bucket slot: gbase[b] + block-internal offset[w][j][b] + rank.
// LDS <1KB (max occupancy), 2 barriers/block, zero LDS atomics, writes are
// rank-consecutive within a wave (coalesce into few lines per bucket).
// ---------------------------------------------------------------------------
__global__ __launch_bounds__(K1_THREADS) void v5_bucketize(
        const float* __restrict__ x,
        const float* __restrict__ edges,
        const int*   __restrict__ senders,
        const int*   __restrict__ receivers,
        const float* __restrict__ w_node,
        const float* __restrict__ w_edge,
        int*   __restrict__ cnt,
        float* __restrict__ ovf,
        int*   __restrict__ bkt) {
    __shared__ int s_cnt[NW][K1_ROUNDS][NR];
    __shared__ int s_off[NW][K1_ROUNDS][NR];
    __shared__ int s_gbase[NR];

    const float wn = w_node[0];
    const float we = w_edge[0];
    const int tile = blockIdx.x * K1_EDGES;      // 3125*1024 == N_EDGES exact
    const int tid  = (int)threadIdx.x;
    const int lane = tid & 63;
    const int wv   = tid >> 6;
    const unsigned long long lt = (1ull << lane) - 1ull;

    // all global loads issued up front: lane-contiguous edge lines (16KB/wave)
    int rr[K1_ROUNDS]; float mm[K1_ROUNDS];
#pragma unroll
    for (int j = 0; j < K1_ROUNDS; ++j) {
        int e    = tile + j * K1_THREADS + tid;
        rr[j]    = __builtin_nontemporal_load(receivers + e);
        int s    = __builtin_nontemporal_load(senders + e);
        float ev = __builtin_nontemporal_load(edges + (size_t)e * D_EDGE);
        mm[j] = we * ev + wn * x[s];
    }

    // pass A: ballot counts + ranks, registers only
    int rk[K1_ROUNDS]; int wc[K1_ROUNDS];        // wc meaningful on lanes<NR
#pragma unroll
    for (int j = 0; j < K1_ROUNDS; ++j) {
        const int b = rr[j] >> 14;               // SPAN = 2^14
        int rank = 0, cnt_k = 0;
#pragma unroll
        for (int k = 0; k < NR; ++k) {
            unsigned long long mk = __ballot(b == k);
            if (k == b)    rank  = __popcll(mk & lt);
            if (lane == k) cnt_k = __popcll(mk);
        }
        rk[j] = rank; wc[j] = cnt_k;
    }
    if (lane < NR) {
#pragma unroll
        for (int j = 0; j < K1_ROUNDS; ++j) s_cnt[wv][j][lane] = wc[j];
    }
    __syncthreads();

    if (tid < NR) {                              // block-internal exclusive scan
        int base = 0;
#pragma unroll
        for (int j = 0; j < K1_ROUNDS; ++j)
#pragma unroll
            for (int w = 0; w < NW; ++w) { s_off[w][j][tid] = base; base += s_cnt[w][j][tid]; }
        s_gbase[tid] = atomicAdd(&cnt[tid], base);
    }
    __syncthreads();

    // pass B: direct global scatter, positions deterministic
#pragma unroll
    for (int j = 0; j < K1_ROUNDS; ++j) {
        const int b = rr[j] >> 14;
        int pos = s_gbase[b] + s_off[wv][j][b] + rk[j];
        iv2 v; v.x = rr[j] & (SPAN - 1); v.y = __float_as_int(mm[j]);
        if (pos < CAP) *(iv2*)(bkt + ((size_t)b * CAP + pos) * 2) = v;
        else atomicAdd(&ovf[b * SPAN + v.x], __int_as_float(v.y));
    }
}

// ---------------------------------------------------------------------------
// K2: grid (NSLICE, NR). Block (s,r) reads its contiguous slice of bucket r
// once, LDS-atomicAdds into the 64KB range accumulator, overwrites its span
// of partials row s. (unchanged from round 5 — single-variable experiment)
// ---------------------------------------------------------------------------
__global__ __launch_bounds__(1024) void v5_accum(
        const int* __restrict__ bkt,
        const int* __restrict__ cnt,
        float* __restrict__ partials) {
    extern __shared__ float acc[];               // SPAN floats = 64 KB dynamic
    const int r  = blockIdx.y;
    const int lo = r * SPAN;
    int span = N_NODES - lo; if (span > SPAN) span = SPAN;

    const int n     = cnt[r];
    const int chunk = (n + NSLICE - 1) / NSLICE;
    int start = blockIdx.x * chunk;
    int end   = start + chunk; if (end > n) end = n;

    for (int i = threadIdx.x * 4; i < SPAN; i += 4096) {
        fv4 z = {0.f, 0.f, 0.f, 0.f};
        *(fv4*)(acc + i) = z;
    }
    __syncthreads();

    const int* base = bkt + (size_t)r * CAP * 2;
    for (int i = start + (int)threadIdx.x; i < end; i += 1024) {
        iv2 v = *(const iv2*)(base + (size_t)i * 2);
        atomicAdd(&acc[v.x], __int_as_float(v.y));
    }
    __syncthreads();

    float* dst = partials + (size_t)blockIdx.x * N_NODES + lo;
    for (int i = threadIdx.x * 4; i < span; i += 4096)   // span % 4 == 0
        *(fv4*)(dst + i) = *(const fv4*)(acc + i);
}

// ---------------------------------------------------------------------------
// K3: out[i] = wn*x[i] + b + ovf[i] + sum_s partials[s][i].
// ---------------------------------------------------------------------------
__global__ void v5_out(const float* __restrict__ x,
                       const float* __restrict__ partials,
                       const float* __restrict__ ovf,
                       const float* __restrict__ w_node,
                       const float* __restrict__ b_node,
                       float* __restrict__ out) {
    int i = blockIdx.x * blockDim.x + threadIdx.x;
    if (i >= N_NODES) return;
    float s = w_node[0] * x[i] + b_node[0] + ovf[i];
#pragma unroll 8
    for (int c = 0; c < NSLICE; ++c) s += partials[(size_t)c * N_NODES + i];
    out[i] = s;
}

// ---------------------------------------------------------------------------
// Fallback (workspace too small): direct atomic path (known-correct).
// ---------------------------------------------------------------------------
__global__ void tmp_init_out(const float* __restrict__ nodes,
                             const float* __restrict__ w_node,
                             const float* __restrict__ b_node,
                             float* __restrict__ out) {
    int i = blockIdx.x * blockDim.x + threadIdx.x;
    if (i < N_NODES) out[i] = w_node[0] * nodes[(size_t)i * D_NODE] + b_node[0];
}

__global__ void tmp_edge_scatter_direct(const float* __restrict__ nodes,
                                        const float* __restrict__ edges,
                                        const int*   __restrict__ senders,
                                        const int*   __restrict__ receivers,
                                        const float* __restrict__ w_node,
                                        const float* __restrict__ w_edge,
                                        float* __restrict__ out) {
    const float wn = w_node[0];
    const float we = w_edge[0];
    int base = (blockIdx.x * blockDim.x + threadIdx.x) * 4;
    if (base + 3 < N_EDGES) {
        iv4 s = *(const iv4*)(senders + base);
        iv4 r = *(const iv4*)(receivers + base);
        atomicAdd(&out[r.x], we * edges[(size_t)(base + 0) * D_EDGE] + wn * nodes[(size_t)s.x * D_NODE]);
        atomicAdd(&out[r.y], we * edges[(size_t)(base + 1) * D_EDGE] + wn * nodes[(size_t)s.y * D_NODE]);
        atomicAdd(&out[r.z], we * edges[(size_t)(base + 2) * D_EDGE] + wn * nodes[(size_t)s.z * D_NODE]);
        atomicAdd(&out[r.w], we * edges[(size_t)(base + 3) * D_EDGE] + wn * nodes[(size_t)s.w * D_NODE]);
    } else {
        for (int e = base; e < N_EDGES; ++e) {
            atomicAdd(&out[receivers[e]],
                      we * edges[(size_t)e * D_EDGE] + wn * nodes[(size_t)senders[e] * D_NODE]);
        }
    }
}

extern "C" void kernel_launch(void* const* d_in, const int* in_sizes, int n_in,
                              void* d_out, int out_size, void* d_ws, size_t ws_size,
                              hipStream_t stream) {
    const float* nodes     = (const float*)d_in[0];
    const float* edges     = (const float*)d_in[1];
    const int*   senders   = (const int*)d_in[2];
    const int*   receivers = (const int*)d_in[3];
    const float* w_node    = (const float*)d_in[4];
    const float* w_edge    = (const float*)d_in[5];
    const float* b_node    = (const float*)d_in[6];
    float* out = (float*)d_out;
    float* ws  = (float*)d_ws;

    if (ws_size >= (size_t)WS_TOTAL * sizeof(float)) {
        float* x    = ws + WS_X;
        int*   cnt  = (int*)(ws + WS_CNT);
        float* ovf  = ws + WS_OVF;
        int*   bkt  = (int*)(ws + WS_BKT);
        float* part = ws + WS_PART;

        int threads = 256;
        v5_init<<<(N_NODES + threads - 1) / threads, threads, 0, stream>>>(
            nodes, x, ovf, cnt);

        v5_bucketize<<<N_EDGES / K1_EDGES, K1_THREADS, 0, stream>>>(
            x, edges, senders, receivers, w_node, w_edge, cnt, ovf, bkt);

        dim3 grid2(NSLICE, NR);
        v5_accum<<<grid2, 1024, SPAN * sizeof(float), stream>>>(bkt, cnt, part);

        v5_out<<<(N_NODES + threads - 1) / threads, threads, 0, stream>>>(
            x, part, ovf, w_node, b_node, out);
    } else {
        int threads = 256;
        tmp_init_out<<<(N_NODES + threads - 1) / threads, threads, 0, stream>>>(
            nodes, w_node, b_node, out);
        int n_thr = N_EDGES / 4;
        tmp_edge_scatter_direct<<<(n_thr + threads - 1) / threads, threads, 0, stream>>>(
            nodes, edges, senders, receivers, w_node, w_edge, out);
    }
}

// Round 8
// 349.255 us; speedup vs baseline: 1.1156x; 1.0260x over previous
//
#include <hip/hip_runtime.h>

#define N_NODES 100000
#define N_EDGES 3200000
#define D_NODE 128
#define D_EDGE 16

#define NR 7                 // node ranges == buckets; SPAN*NR >= N_NODES
#define SPAN 16384           // pow2: bucket = r>>14, local = r & 16383
#define CAP 560000           // per-bucket capacity (expected 524288, ~54 sigma margin)
#define NSLICE 32            // K2 blocks per range -> 224 blocks; partials 12.8MB

#define CNT_STRIDE 16        // one counter per 64B line: kills same-line TCC serialization

#define K1_THREADS 512
#define K1_EDGES 2560        // 3.2M / 2560 = 1250 blocks exact
#define NW (K1_THREADS / 64) // 8 waves
#define K1_ROUNDS (K1_EDGES / K1_THREADS)   // 5

// ---- ws layout (float units) ----
#define WS_X     0                         // 100000: compacted nodes[:,0]
#define WS_CNT   100000                    // NR*CNT_STRIDE ints (padded counters)
#define WS_OVF   100128                    // 100000: overflow accumulator (stat. never)
#define WS_BKT   200128                    // NR*CAP*2 floats of (local,msg) pairs
#define WS_PART  (WS_BKT + NR * CAP * 2)   // NSLICE rows x N_NODES partials
#define WS_TOTAL (WS_PART + NSLICE * N_NODES)

// clang-native vectors (__builtin_nontemporal_load rejects HIP's class-type int4)
typedef int   iv2 __attribute__((ext_vector_type(2)));
typedef int   iv4 __attribute__((ext_vector_type(4)));
typedef float fv4 __attribute__((ext_vector_type(4)));

// ---------------------------------------------------------------------------
// K0: zero padded counters + overflow acc, compact node column.
// ---------------------------------------------------------------------------
__global__ void v6_init(const float* __restrict__ nodes,
                        float* __restrict__ x,
                        float* __restrict__ ovf,
                        int*   __restrict__ cnt) {
    int i = blockIdx.x * blockDim.x + threadIdx.x;
    if (i < NR * CNT_STRIDE) cnt[i] = 0;
    if (i < N_NODES) {
        x[i]   = nodes[(size_t)i * D_NODE];
        ovf[i] = 0.f;
    }
}

// ---------------------------------------------------------------------------
// K1 v6: count-then-write-direct bucketize (v5 structure) with de-contended
// counters. Round-7 post-mortem: cnt[0..6] shared ONE 64B line -> 21.9K
// same-line memory-side RMWs serialized on one TCC (~1ns each, ~22us, on the
// critical path; round-6's 2x block count regressing +22us is the fingerprint).
// v6: one counter per 64B line (CNT_STRIDE=16) -> 7 parallel TCC lines, and
// 1250 blocks instead of 3125 -> ~1.25K atomics per line (~2us total).
// ---------------------------------------------------------------------------
__global__ __launch_bounds__(K1_THREADS) void v6_bucketize(
        const float* __restrict__ x,
        const float* __restrict__ edges,
        const int*   __restrict__ senders,
        const int*   __restrict__ receivers,
        const float* __restrict__ w_node,
        const float* __restrict__ w_edge,
        int*   __restrict__ cnt,
        float* __restrict__ ovf,
        int*   __restrict__ bkt) {
    __shared__ int s_cnt[NW][K1_ROUNDS][NR];
    __shared__ int s_off[NW][K1_ROUNDS][NR];
    __shared__ int s_gbase[NR];

    const float wn = w_node[0];
    const float we = w_edge[0];
    const int tile = blockIdx.x * K1_EDGES;      // 1250*2560 == N_EDGES exact
    const int tid  = (int)threadIdx.x;
    const int lane = tid & 63;
    const int wv   = tid >> 6;
    const unsigned long long lt = (1ull << lane) - 1ull;

    // all global loads issued up front: lane-contiguous edge lines
    int rr[K1_ROUNDS]; float mm[K1_ROUNDS];
#pragma unroll
    for (int j = 0; j < K1_ROUNDS; ++j) {
        int e    = tile + j * K1_THREADS + tid;
        rr[j]    = __builtin_nontemporal_load(receivers + e);
        int s    = __builtin_nontemporal_load(senders + e);
        float ev = __builtin_nontemporal_load(edges + (size_t)e * D_EDGE);
        mm[j] = we * ev + wn * x[s];
    }

    // pass A: ballot counts + ranks, registers only
    int rk[K1_ROUNDS]; int wc[K1_ROUNDS];        // wc meaningful on lanes<NR
#pragma unroll
    for (int j = 0; j < K1_ROUNDS; ++j) {
        const int b = rr[j] >> 14;               // SPAN = 2^14
        int rank = 0, cnt_k = 0;
#pragma unroll
        for (int k = 0; k < NR; ++k) {
            unsigned long long mk = __ballot(b == k);
            if (k == b)    rank  = __popcll(mk & lt);
            if (lane == k) cnt_k = __popcll(mk);
        }
        rk[j] = rank; wc[j] = cnt_k;
    }
    if (lane < NR) {
#pragma unroll
        for (int j = 0; j < K1_ROUNDS; ++j) s_cnt[wv][j][lane] = wc[j];
    }
    __syncthreads();

    if (tid < NR) {                              // block-internal exclusive scan
        int base = 0;
#pragma unroll
        for (int j = 0; j < K1_ROUNDS; ++j)
#pragma unroll
            for (int w = 0; w < NW; ++w) { s_off[w][j][tid] = base; base += s_cnt[w][j][tid]; }
        s_gbase[tid] = atomicAdd(&cnt[tid * CNT_STRIDE], base);
    }
    __syncthreads();

    // pass B: direct global scatter, positions deterministic
#pragma unroll
    for (int j = 0; j < K1_ROUNDS; ++j) {
        const int b = rr[j] >> 14;
        int pos = s_gbase[b] + s_off[wv][j][b] + rk[j];
        iv2 v; v.x = rr[j] & (SPAN - 1); v.y = __float_as_int(mm[j]);
        if (pos < CAP) *(iv2*)(bkt + ((size_t)b * CAP + pos) * 2) = v;
        else atomicAdd(&ovf[b * SPAN + v.x], __int_as_float(v.y));
    }
}

// ---------------------------------------------------------------------------
// K2: grid (NSLICE, NR). Block (s,r) reads its contiguous slice of bucket r
// once, LDS-atomicAdds into the 64KB range accumulator, overwrites its span
// of partials row s. NSLICE halved vs round 7: partials 25.6->12.8MB and
// per-range zero/flush fixed costs halve; 224 blocks still fill the chip.
// ---------------------------------------------------------------------------
__global__ __launch_bounds__(1024) void v6_accum(
        const int* __restrict__ bkt,
        const int* __restrict__ cnt,
        float* __restrict__ partials) {
    extern __shared__ float acc[];               // SPAN floats = 64 KB dynamic
    const int r  = blockIdx.y;
    const int lo = r * SPAN;
    int span = N_NODES - lo; if (span > SPAN) span = SPAN;

    const int n     = cnt[r * CNT_STRIDE];
    const int chunk = (n + NSLICE - 1) / NSLICE;
    int start = blockIdx.x * chunk;
    int end   = start + chunk; if (end > n) end = n;

    for (int i = threadIdx.x * 4; i < SPAN; i += 4096) {
        fv4 z = {0.f, 0.f, 0.f, 0.f};
        *(fv4*)(acc + i) = z;
    }
    __syncthreads();

    const int* base = bkt + (size_t)r * CAP * 2;
    for (int i = start + (int)threadIdx.x; i < end; i += 1024) {
        iv2 v = *(const iv2*)(base + (size_t)i * 2);
        atomicAdd(&acc[v.x], __int_as_float(v.y));
    }
    __syncthreads();

    float* dst = partials + (size_t)blockIdx.x * N_NODES + lo;
    for (int i = threadIdx.x * 4; i < span; i += 4096)   // span % 4 == 0
        *(fv4*)(dst + i) = *(const fv4*)(acc + i);
}

// ---------------------------------------------------------------------------
// K3: out[i] = wn*x[i] + b + ovf[i] + sum_s partials[s][i].
// ---------------------------------------------------------------------------
__global__ void v6_out(const float* __restrict__ x,
                       const float* __restrict__ partials,
                       const float* __restrict__ ovf,
                       const float* __restrict__ w_node,
                       const float* __restrict__ b_node,
                       float* __restrict__ out) {
    int i = blockIdx.x * blockDim.x + threadIdx.x;
    if (i >= N_NODES) return;
    float s = w_node[0] * x[i] + b_node[0] + ovf[i];
#pragma unroll 8
    for (int c = 0; c < NSLICE; ++c) s += partials[(size_t)c * N_NODES + i];
    out[i] = s;
}

// ---------------------------------------------------------------------------
// Fallback (workspace too small): direct atomic path (known-correct).
// ---------------------------------------------------------------------------
__global__ void tmp_init_out(const float* __restrict__ nodes,
                             const float* __restrict__ w_node,
                             const float* __restrict__ b_node,
                             float* __restrict__ out) {
    int i = blockIdx.x * blockDim.x + threadIdx.x;
    if (i < N_NODES) out[i] = w_node[0] * nodes[(size_t)i * D_NODE] + b_node[0];
}

__global__ void tmp_edge_scatter_direct(const float* __restrict__ nodes,
                                        const float* __restrict__ edges,
                                        const int*   __restrict__ senders,
                                        const int*   __restrict__ receivers,
                                        const float* __restrict__ w_node,
                                        const float* __restrict__ w_edge,
                                        float* __restrict__ out) {
    const float wn = w_node[0];
    const float we = w_edge[0];
    int base = (blockIdx.x * blockDim.x + threadIdx.x) * 4;
    if (base + 3 < N_EDGES) {
        iv4 s = *(const iv4*)(senders + base);
        iv4 r = *(const iv4*)(receivers + base);
        atomicAdd(&out[r.x], we * edges[(size_t)(base + 0) * D_EDGE] + wn * nodes[(size_t)s.x * D_NODE]);
        atomicAdd(&out[r.y], we * edges[(size_t)(base + 1) * D_EDGE] + wn * nodes[(size_t)s.y * D_NODE]);
        atomicAdd(&out[r.z], we * edges[(size_t)(base + 2) * D_EDGE] + wn * nodes[(size_t)s.z * D_NODE]);
        atomicAdd(&out[r.w], we * edges[(size_t)(base + 3) * D_EDGE] + wn * nodes[(size_t)s.w * D_NODE]);
    } else {
        for (int e = base; e < N_EDGES; ++e) {
            atomicAdd(&out[receivers[e]],
                      we * edges[(size_t)e * D_EDGE] + wn * nodes[(size_t)senders[e] * D_NODE]);
        }
    }
}

extern "C" void kernel_launch(void* const* d_in, const int* in_sizes, int n_in,
                              void* d_out, int out_size, void* d_ws, size_t ws_size,
                              hipStream_t stream) {
    const float* nodes     = (const float*)d_in[0];
    const float* edges     = (const float*)d_in[1];
    const int*   senders   = (const int*)d_in[2];
    const int*   receivers = (const int*)d_in[3];
    const float* w_node    = (const float*)d_in[4];
    const float* w_edge    = (const float*)d_in[5];
    const float* b_node    = (const float*)d_in[6];
    float* out = (float*)d_out;
    float* ws  = (float*)d_ws;

    if (ws_size >= (size_t)WS_TOTAL * sizeof(float)) {
        float* x    = ws + WS_X;
        int*   cnt  = (int*)(ws + WS_CNT);
        float* ovf  = ws + WS_OVF;
        int*   bkt  = (int*)(ws + WS_BKT);
        float* part = ws + WS_PART;

        int threads = 256;
        v6_init<<<(N_NODES + threads - 1) / threads, threads, 0, stream>>>(
            nodes, x, ovf, cnt);

        v6_bucketize<<<N_EDGES / K1_EDGES, K1_THREADS, 0, stream>>>(
            x, edges, senders, receivers, w_node, w_edge, cnt, ovf, bkt);

        dim3 grid2(NSLICE, NR);
        v6_accum<<<grid2, 1024, SPAN * sizeof(float), stream>>>(bkt, cnt, part);

        v6_out<<<(N_NODES + threads - 1) / threads, threads, 0, stream>>>(
            x, part, ovf, w_node, b_node, out);
    } else {
        int threads = 256;
        tmp_init_out<<<(N_NODES + threads - 1) / threads, threads, 0, stream>>>(
            nodes, w_node, b_node, out);
        int n_thr = N_EDGES / 4;
        tmp_edge_scatter_direct<<<(n_thr + threads - 1) / threads, threads, 0, stream>>>(
            nodes, edges, senders, receivers, w_node, w_edge, out);
    }
}